// Round 12
// baseline (349.877 us; speedup 1.0000x reference)
//
#include <hip/hip_runtime.h>

#define N_PTS 1000000
#define H_DIM 200
#define W_DIM 70400
#define FILL_V -9999999.0f

typedef float v2f __attribute__((ext_vector_type(2)));

__device__ __forceinline__ v2f fma2(v2f a, v2f b, v2f c) {
    return __builtin_elementwise_fma(a, b, c);   // -> v_pk_fma_f32 on gfx950
}
__device__ __forceinline__ v2f lo2(float4 f) { v2f r = { f.x, f.y }; return r; }
__device__ __forceinline__ v2f hi2(float4 f) { v2f r = { f.z, f.w }; return r; }

// ---------------------------------------------------------------------------
// Kernel A: per-point MLP (4->18->36->36->1), ONE point per thread, k-packed
// v2f math (v_pk_fma_f32), layer 4 fused into layer 3.
// R10 (scalar s_load weights) was latency-bound on the scalar stream:
// VALUBusy 37%, the 112-SGPR window feeds ~8 pk_fma per s_waitcnt. Here the
// weight pointers carry an OPAQUE VGPR ZERO (inline asm) so the compiler
// cannot prove uniformity and must emit global_load_dwordx4: uniform-address
// wave loads coalesce to 1 L1 access + broadcast, the vmcnt window is deep,
// and weights land in free VGPRs (R10: 60 used). ~344 float4 loads vs ~1010
// pk_fma per point. w2 is read in 2-row blocks (144 B = 9 aligned float4),
// w3 per-row (144 B/row). Biases stay scalar.
// DO NOT raise the per-thread live set: every variant that exceeded ~60 live
// floats (R3/R4/R8-LDS/R11-2pt) got AGPR- or scratch-spilled by the
// allocator regardless of __launch_bounds__ (worst: 9 GB HBM, 3.3 ms).
// List entry: .x = value bits, .y = (point_index << 8) | row  (row<200<256).
// Last-write-wins scatter: point survives iff no LATER point hit (row,col).
// ---------------------------------------------------------------------------
__global__ void __launch_bounds__(256) mlp_scatter_kernel(
    const float* __restrict__ input,        // [4][N]
    const int* __restrict__ tindex,         // [N][2] int32 (row, col)
    const float* __restrict__ w1, const float* __restrict__ b1,
    const float* __restrict__ w2, const float* __restrict__ b2,
    const float* __restrict__ w3, const float* __restrict__ b3,
    const float* __restrict__ w4, const float* __restrict__ b4,
    int* __restrict__ counts,               // [W]
    uint2* __restrict__ list,               // [W][maxk]
    int maxk)
{
    // empty-branch (reference: tensor_index[0,0] == -1 -> no scatter)
    if (tindex[0] == -1) return;

    const int i = blockIdx.x * 256 + threadIdx.x;
    if (i >= N_PTS) return;

    // opaque zero living in a VGPR: defeats uniform-address scalarization
    int vzero;
    asm volatile("v_mov_b32 %0, 0" : "=v"(vzero));

    const float4* __restrict__ w1q = (const float4*)w1 + vzero;  // 18 float4
    const float4* __restrict__ w2q = (const float4*)w2 + vzero;  // 162
    const float4* __restrict__ w3q = (const float4*)w3 + vzero;  // 324

    const v2f x01 = { input[0 * N_PTS + i], input[1 * N_PTS + i] };
    const v2f x23 = { input[2 * N_PTS + i], input[3 * N_PTS + i] };

    // layer 1: 18 outputs; row o = w1q[o] (16 B per row, aligned)
    v2f h1v[9];
#pragma unroll
    for (int p = 0; p < 9; ++p) {            // outputs 2p, 2p+1
        const float4 fa = w1q[2 * p], fb = w1q[2 * p + 1];
        v2f a0 = { b1[2 * p], 0.0f };
        v2f a1 = { b1[2 * p + 1], 0.0f };
        a0 = fma2(lo2(fa), x01, a0); a0 = fma2(hi2(fa), x23, a0);
        a1 = fma2(lo2(fb), x01, a1); a1 = fma2(hi2(fb), x23, a1);
        h1v[p].x = fmaxf(a0.x + a0.y, 0.0f);
        h1v[p].y = fmaxf(a1.x + a1.y, 0.0f);
    }

    // layer 2: 36 outputs; 2-row block p = w2q[9p .. 9p+8]
    // (block = 36 floats = 18 v2f; row 2p = v2f 0..8, row 2p+1 = v2f 9..17)
    v2f h2v[18];
#pragma unroll
    for (int p = 0; p < 18; ++p) {
        const float4* blk = w2q + p * 9;
        v2f a0 = { b2[2 * p], 0.0f };
        v2f a1 = { b2[2 * p + 1], 0.0f };
#pragma unroll
        for (int q = 0; q < 4; ++q) {        // v2f 0..7 -> row 2p, k-pairs 0..7
            const float4 f = blk[q];
            a0 = fma2(lo2(f), h1v[2 * q], a0);
            a0 = fma2(hi2(f), h1v[2 * q + 1], a0);
        }
        {
            const float4 f = blk[4];         // v2f 8 (row 2p), v2f 9 (row 2p+1)
            a0 = fma2(lo2(f), h1v[8], a0);
            a1 = fma2(hi2(f), h1v[0], a1);
        }
#pragma unroll
        for (int q = 5; q < 9; ++q) {        // v2f 10..17 -> row 2p+1, pairs 1..8
            const float4 f = blk[q];
            a1 = fma2(lo2(f), h1v[2 * q - 9], a1);
            a1 = fma2(hi2(f), h1v[2 * q - 8], a1);
        }
        h2v[p].x = fmaxf(a0.x + a0.y, 0.0f);
        h2v[p].y = fmaxf(a1.x + a1.y, 0.0f);
    }

    // layer 3 (row o = w3q[9o .. 9o+8], 144 B aligned) with layer 4 fused
    float v = b4[0];
#pragma unroll
    for (int o = 0; o < 36; ++o) {
        const float4* row = w3q + o * 9;
        v2f acc = { b3[o], 0.0f };
#pragma unroll
        for (int q = 0; q < 9; ++q) {
            const float4 f = row[q];
            acc = fma2(lo2(f), h2v[2 * q], acc);
            acc = fma2(hi2(f), h2v[2 * q + 1], acc);
        }
        v = fmaf(w4[o], fmaxf(acc.x + acc.y, 0.0f), v);
    }

    const int2 hw = ((const int2*)tindex)[i];   // (row, col)
    const int pos = atomicAdd(&counts[hw.y], 1);
    if (pos < maxk) {   // never overflows statistically at maxk>=64 (mean 14.2/col)
        uint2 e;
        e.x = __float_as_uint(v);
        e.y = ((unsigned)i << 8) | (unsigned)hw.x;
        list[(size_t)hw.y * maxk + pos] = e;
    }
}

// ---------------------------------------------------------------------------
// Kernel B: block (64,4) = 4 waves, one column per wave. Lane a holds slot a
// (one coalesced load per wave). Dedup via 64-bit per-wave winner table:
// atomicMax(tbl64[row], (key<<32)|value_bits); high word (i<<8|row) orders by
// point index, low word carries the winner's value. After __syncthreads(),
// each lane reads its row's winner VALUE; duplicate reads of the same winner
// are harmless under max. (R4/R5 bug: init must cover all 200 rows -- 64
// lanes need 4 strided passes.) Verified correct R6-R11.
// ---------------------------------------------------------------------------
__global__ void __launch_bounds__(256) colmax_kernel(
    const int* __restrict__ tindex,
    const int* __restrict__ counts,
    const uint2* __restrict__ list,
    float* __restrict__ out,
    int maxk)
{
    __shared__ unsigned long long rowwin[4][200];
    const int lane = threadIdx.x;        // 0..63
    const int y    = threadIdx.y;        // 0..3
    const int w    = blockIdx.x * 4 + y; // column id, always < W_DIM (70400=4*17600)

    const bool empty = (tindex[0] == -1);

    if (blockIdx.x == 0 && lane == 0 && y == 0)
        out[W_DIM] = empty ? 0.0f : 1.0f;    // flag output

    int c = 0;
    if (!empty) {
        c = counts[w];
        if (c > maxk) c = maxk;
    }

    unsigned long long* tbl = rowwin[y];
    tbl[lane]       = 0ull;                  // rows   0.. 63
    tbl[lane + 64]  = 0ull;                  // rows  64..127
    tbl[lane + 128] = 0ull;                  // rows 128..191
    if (lane < 8) tbl[lane + 192] = 0ull;    // rows 192..199
    __syncthreads();

    uint2 e = make_uint2(0u, 0u);
    const bool have = (lane < c);
    if (have) {
        e = list[(size_t)w * maxk + lane];
        const unsigned long long key64 =
            ((unsigned long long)e.y << 32) | (unsigned long long)e.x;
        atomicMax(&tbl[e.y & 0xFFu], key64);
    }
    __syncthreads();

    float v = FILL_V;
    if (have) {
        const unsigned long long winner = tbl[e.y & 0xFFu];
        v = __uint_as_float((unsigned)(winner & 0xFFFFFFFFull));
    }
#pragma unroll
    for (int off = 32; off > 0; off >>= 1)
        v = fmaxf(v, __shfl_down(v, off, 64));

    if (lane == 0) out[w] = v;
}

extern "C" void kernel_launch(void* const* d_in, const int* in_sizes, int n_in,
                              void* d_out, int out_size, void* d_ws, size_t ws_size,
                              hipStream_t stream) {
    const float* input  = (const float*)d_in[0];
    const int*   tindex = (const int*)d_in[1];   // int32 on device
    const float* w1 = (const float*)d_in[2];
    const float* b1 = (const float*)d_in[3];
    const float* w2 = (const float*)d_in[4];
    const float* b2 = (const float*)d_in[5];
    const float* w3 = (const float*)d_in[6];
    const float* b3 = (const float*)d_in[7];
    const float* w4 = (const float*)d_in[8];
    const float* b4 = (const float*)d_in[9];
    float* out = (float*)d_out;

    // workspace: counts [70400 int] | list [70400][maxk] uint2
    int*   counts = (int*)d_ws;
    uint2* list   = (uint2*)((char*)d_ws + (size_t)W_DIM * sizeof(int));

    size_t avail = (ws_size > (size_t)W_DIM * sizeof(int))
                       ? ws_size - (size_t)W_DIM * sizeof(int) : 0;
    int maxk = (int)(avail / ((size_t)W_DIM * sizeof(uint2)));
    if (maxk > 64) maxk = 64;
    if (maxk < 1)  maxk = 1;

    hipMemsetAsync(counts, 0, (size_t)W_DIM * sizeof(int), stream);

    mlp_scatter_kernel<<<(N_PTS + 255) / 256, 256, 0, stream>>>(
        input, tindex, w1, b1, w2, b2, w3, b3, w4, b4, counts, list, maxk);

    // one wave per column, 4 waves per block; 70400/4 = 17600 exact blocks
    colmax_kernel<<<W_DIM / 4, dim3(64, 4), 0, stream>>>(
        tindex, counts, list, out, maxk);
}